// Round 1
// baseline (622.516 us; speedup 1.0000x reference)
//
#include <hip/hip_runtime.h>
#include <hip/hip_bf16.h>
#include <stdint.h>

#define TT 2048
#define BB 2
#define CC 1024
#define NEGF (-1e30f)

typedef short bf16x8 __attribute__((ext_vector_type(8)));
typedef float f32x4 __attribute__((ext_vector_type(4)));

__device__ __forceinline__ f32x4 mfma16(bf16x8 a, bf16x8 b, f32x4 c) {
  return __builtin_amdgcn_mfma_f32_16x16x32_bf16(a, b, c, 0, 0, 0);
}

__device__ __forceinline__ uint16_t f2bf(float f) {
  union { float f; uint32_t u; } v; v.f = f;
  uint32_t u = v.u;
  return (uint16_t)((u + 0x7FFFu + ((u >> 16) & 1u)) >> 16);
}

// ---- x f32 -> bf16 ----
__global__ __launch_bounds__(256) void k_convert(const float* __restrict__ in,
                                                 uint16_t* __restrict__ out, int n4) {
  int i = blockIdx.x * blockDim.x + threadIdx.x;
  if (i >= n4) return;
  float4 f = ((const float4*)in)[i];
  ushort4 o;
  o.x = f2bf(f.x); o.y = f2bf(f.y); o.z = f2bf(f.z); o.w = f2bf(f.w);
  ((ushort4*)out)[i] = o;
}

// ---- W [K][N] f32 -> Wt [N][K] bf16 (LDS-tiled transpose) ----
__global__ __launch_bounds__(256) void k_transpose(const float* __restrict__ W,
                                                   uint16_t* __restrict__ Wt,
                                                   int K, int N) {
  __shared__ float tile[32][33];
  int tx = threadIdx.x & 31, ty = threadIdx.x >> 5;
  int n0 = blockIdx.x * 32, k0 = blockIdx.y * 32;
#pragma unroll
  for (int r = 0; r < 4; r++)
    tile[ty + r * 8][tx] = W[(size_t)(k0 + ty + r * 8) * N + n0 + tx];
  __syncthreads();
#pragma unroll
  for (int r = 0; r < 4; r++)
    Wt[(size_t)(n0 + ty + r * 8) * K + k0 + tx] = f2bf(tile[tx][ty + r * 8]);
}

// ---- GEMM: C[M][ldc] = A[M][K] * Bt[N][K]^T, bf16 in, bf16 or f32 out ----
// block = 4 waves; block tile 64(M) x 64(N); wave tile 16 x 64.
template <bool F32OUT>
__global__ __launch_bounds__(256) void k_gemm(const uint16_t* __restrict__ A,
                                              const uint16_t* __restrict__ Bt,
                                              void* __restrict__ Cp,
                                              int K, int ldc) {
  int lane = threadIdx.x & 63, wave = threadIdx.x >> 6;
  int lr = lane & 15, lg = lane >> 4;
  int m0 = blockIdx.y * 64 + wave * 16;
  int n0 = blockIdx.x * 64;
  f32x4 acc[4] = {};
  const uint16_t* pa = A + (size_t)(m0 + lr) * K + lg * 8;
  const uint16_t* pb = Bt + (size_t)(n0 + lr) * K + lg * 8;
#pragma unroll 4
  for (int k = 0; k < K; k += 32) {
    bf16x8 af = *(const bf16x8*)(pa + k);
#pragma unroll
    for (int c = 0; c < 4; c++) {
      bf16x8 bf = *(const bf16x8*)(pb + (size_t)c * 16 * K + k);
      acc[c] = mfma16(af, bf, acc[c]);
    }
  }
#pragma unroll
  for (int c = 0; c < 4; c++)
#pragma unroll
    for (int r = 0; r < 4; r++) {
      size_t idx = (size_t)(m0 + lg * 4 + r) * ldc + n0 + c * 16 + lr;
      if (F32OUT) ((float*)Cp)[idx] = acc[c][r];
      else        ((uint16_t*)Cp)[idx] = f2bf(acc[c][r]);
    }
}

// ---- windowed causal flash attention, both head types ----
// QKV: [B*T][2560] bf16 rows:
//   full h<8:  q = h*64, k = 512+h*64, v = 1024+h*64   (dqk=64, win=1024)
//   red  h>=8: q = 1536+hr*32, k = 1792+hr*32, v = 2048+hr*64 (dqk=32, win=256)
// Y: [B*T][1024] bf16, head h occupies cols h*64..h*64+63
__global__ __launch_bounds__(256) void k_attn(const uint16_t* __restrict__ QKV,
                                              uint16_t* __restrict__ Y) {
  __shared__ __align__(16) uint16_t Vlds[4][32][64];
  __shared__ __align__(16) uint16_t Plds[4][16][32];
  int lane = threadIdx.x & 63, wave = threadIdx.x >> 6;
  int lr = lane & 15, lg = lane >> 4;
  int qt = blockIdx.x & 31;          // T/64 = 32
  int h = (blockIdx.x >> 5) & 15;
  int b = blockIdx.x >> 9;
  int q0 = qt * 64 + wave * 16;

  int dqk, window, qOff, kOff, vOff;
  if (h < 8) { dqk = 64; window = 1024; qOff = h * 64; kOff = 512 + h * 64; vOff = 1024 + h * 64; }
  else { int hr = h - 8; dqk = 32; window = 256; qOff = 1536 + hr * 32; kOff = 1792 + hr * 32; vOff = 2048 + hr * 64; }
  float scale = (dqk == 64) ? 0.125f : 0.17677669529663687f;
  const uint16_t* base = QKV + (size_t)b * TT * 2560;
  int nf = dqk >> 5;

  bf16x8 qf[2];
  for (int f = 0; f < nf; f++)
    qf[f] = *(const bf16x8*)(base + (size_t)(q0 + lr) * 2560 + qOff + f * 32 + lg * 8);

  float m[4], l[4];
  f32x4 o[4];
#pragma unroll
  for (int r = 0; r < 4; r++) { m[r] = NEGF; l[r] = 0.f; }
#pragma unroll
  for (int c = 0; c < 4; c++) o[c] = (f32x4){0.f, 0.f, 0.f, 0.f};

  int klo = q0 - window + 1; if (klo < 0) klo = 0; klo &= ~31;
  int khi = q0 + 15;

  for (int k0 = klo; k0 <= khi; k0 += 32) {
    // stage V tile [32 keys][64 dv] into per-wave LDS, coalesced 16B chunks
#pragma unroll
    for (int it = 0; it < 4; it++) {
      int idx = it * 64 + lane;
      int row = idx >> 3, e = (idx & 7) * 8;
      int t = k0 + row; if (t > TT - 1) t = TT - 1;
      *(bf16x8*)&Vlds[wave][row][e] = *(const bf16x8*)(base + (size_t)t * 2560 + vOff + e);
    }
    // S = Q K^T  (two 16-key halves)
    f32x4 s[2];
#pragma unroll
    for (int half = 0; half < 2; half++) {
      f32x4 accs = (f32x4){0.f, 0.f, 0.f, 0.f};
      int t = k0 + half * 16 + lr; if (t > TT - 1) t = TT - 1;
      const uint16_t* kp = base + (size_t)t * 2560 + kOff + lg * 8;
      for (int f = 0; f < nf; f++) {
        bf16x8 kf = *(const bf16x8*)(kp + f * 32);
        accs = mfma16(qf[f], kf, accs);
      }
      s[half] = accs;
    }
    // scale + window mask; tile row-max
    float tmax[4];
#pragma unroll
    for (int r = 0; r < 4; r++) {
      int q = q0 + lg * 4 + r;
#pragma unroll
      for (int half = 0; half < 2; half++) {
        int key = k0 + half * 16 + lr;
        float sv = s[half][r] * scale;
        bool ok = (key <= q) && (q - key < window);
        s[half][r] = ok ? sv : NEGF;
      }
      tmax[r] = fmaxf(s[0][r], s[1][r]);
    }
#pragma unroll
    for (int d = 1; d < 16; d <<= 1)
#pragma unroll
      for (int r = 0; r < 4; r++)
        tmax[r] = fmaxf(tmax[r], __shfl_xor(tmax[r], d));
    // online softmax update; write P (bf16) to LDS
    float rs[4];
#pragma unroll
    for (int r = 0; r < 4; r++) {
      float mn = fmaxf(m[r], tmax[r]);
      float alpha = __expf(m[r] - mn);   // m=NEG,mn=NEG -> exp(0)=1 (state all zero anyway)
      m[r] = mn;
      l[r] *= alpha;
#pragma unroll
      for (int c = 0; c < 4; c++) o[c][r] *= alpha;
      float psum = 0.f;
#pragma unroll
      for (int half = 0; half < 2; half++) {
        float sv = s[half][r];
        float p = (sv > -0.5e30f) ? __expf(sv - mn) : 0.f;
        psum += p;
        Plds[wave][lg * 4 + r][half * 16 + lr] = f2bf(p);
      }
      rs[r] = psum;
    }
#pragma unroll
    for (int d = 1; d < 16; d <<= 1)
#pragma unroll
      for (int r = 0; r < 4; r++)
        rs[r] += __shfl_xor(rs[r], d);
#pragma unroll
    for (int r = 0; r < 4; r++) l[r] += rs[r];

    asm volatile("s_waitcnt lgkmcnt(0)" ::: "memory");
    // PV: A = P [16q x 32k] from LDS; B = V [32k x 16dv] from LDS
    bf16x8 pa = *(const bf16x8*)&Plds[wave][lr][lg * 8];
#pragma unroll
    for (int c = 0; c < 4; c++) {
      bf16x8 vb;
#pragma unroll
      for (int j = 0; j < 8; j++) vb[j] = (short)Vlds[wave][lg * 8 + j][c * 16 + lr];
      o[c] = mfma16(pa, vb, o[c]);
    }
  }
  // epilogue: normalize, write Y
#pragma unroll
  for (int c = 0; c < 4; c++)
#pragma unroll
    for (int r = 0; r < 4; r++) {
      float val = o[c][r] / l[r];
      int t = q0 + lg * 4 + r;
      Y[((size_t)b * TT + t) * CC + h * 64 + c * 16 + lr] = f2bf(val);
    }
}

extern "C" void kernel_launch(void* const* d_in, const int* in_sizes, int n_in,
                              void* d_out, int out_size, void* d_ws, size_t ws_size,
                              hipStream_t stream) {
  const float* x    = (const float*)d_in[0];
  const float* wqkv = (const float*)d_in[1];
  const float* wqk  = (const float*)d_in[2];
  const float* wv   = (const float*)d_in[3];
  const float* wp   = (const float*)d_in[4];

  uint16_t* ws  = (uint16_t*)d_ws;
  uint16_t* xb  = ws;                               // [4096][1024]
  uint16_t* WtA = xb  + (size_t)4096 * 1024;        // [2560][1024]
  uint16_t* WtP = WtA + (size_t)2560 * 1024;        // [1024][1024]
  uint16_t* QKV = WtP + (size_t)1024 * 1024;        // [4096][2560]
  uint16_t* Yb  = QKV + (size_t)4096 * 2560;        // [4096][1024]

  // 1. convert x to bf16
  k_convert<<<4096, 256, 0, stream>>>(x, xb, 4096 * 1024 / 4);
  // 2. transpose+convert weights: [K][N] -> [N][K] bf16
  k_transpose<<<dim3(48, 32), 256, 0, stream>>>(wqkv, WtA, 1024, 1536);
  k_transpose<<<dim3(16, 32), 256, 0, stream>>>(wqk, WtA + (size_t)1536 * 1024, 1024, 512);
  k_transpose<<<dim3(16, 32), 256, 0, stream>>>(wv,  WtA + (size_t)2048 * 1024, 1024, 512);
  k_transpose<<<dim3(32, 32), 256, 0, stream>>>(wp,  WtP, 1024, 1024);
  // 3. fused input projections: QKV[4096][2560]
  k_gemm<false><<<dim3(40, 64), 256, 0, stream>>>(xb, WtA, QKV, 1024, 2560);
  // 4. windowed attention -> Y[4096][1024] bf16
  k_attn<<<1024, 256, 0, stream>>>(QKV, Yb);
  // 5. output projection -> d_out f32
  k_gemm<true><<<dim3(16, 64), 256, 0, stream>>>(Yb, WtP, (float*)d_out, 1024, 1024);
}

// Round 3
// 477.349 us; speedup vs baseline: 1.3041x; 1.3041x over previous
//
#include <hip/hip_runtime.h>
#include <hip/hip_bf16.h>
#include <stdint.h>

#define TT 2048
#define BB 2
#define CC 1024
#define NEGF (-1e30f)

typedef short bf16x8 __attribute__((ext_vector_type(8)));
typedef short bf16x4 __attribute__((ext_vector_type(4)));
typedef float f32x4 __attribute__((ext_vector_type(4)));

__device__ __forceinline__ f32x4 mfma16(bf16x8 a, bf16x8 b, f32x4 c) {
  return __builtin_amdgcn_mfma_f32_16x16x32_bf16(a, b, c, 0, 0, 0);
}

__device__ __forceinline__ uint16_t f2bf(float f) {
  union { float f; uint32_t u; } v; v.f = f;
  uint32_t u = v.u;
  return (uint16_t)((u + 0x7FFFu + ((u >> 16) & 1u)) >> 16);
}

// ---- x f32 -> bf16 ----
__global__ __launch_bounds__(256) void k_convert(const float* __restrict__ in,
                                                 uint16_t* __restrict__ out, int n4) {
  int i = blockIdx.x * blockDim.x + threadIdx.x;
  if (i >= n4) return;
  float4 f = ((const float4*)in)[i];
  ushort4 o;
  o.x = f2bf(f.x); o.y = f2bf(f.y); o.z = f2bf(f.z); o.w = f2bf(f.w);
  ((ushort4*)out)[i] = o;
}

// ---- W [K][N] f32 -> Wt [N][K] bf16 (LDS-tiled transpose) ----
__global__ __launch_bounds__(256) void k_transpose(const float* __restrict__ W,
                                                   uint16_t* __restrict__ Wt,
                                                   int K, int N) {
  __shared__ float tile[32][33];
  int tx = threadIdx.x & 31, ty = threadIdx.x >> 5;
  int n0 = blockIdx.x * 32, k0 = blockIdx.y * 32;
#pragma unroll
  for (int r = 0; r < 4; r++)
    tile[ty + r * 8][tx] = W[(size_t)(k0 + ty + r * 8) * N + n0 + tx];
  __syncthreads();
#pragma unroll
  for (int r = 0; r < 4; r++)
    Wt[(size_t)(n0 + ty + r * 8) * K + k0 + tx] = f2bf(tile[tx][ty + r * 8]);
}

// ---- GEMM: C[M][ldc] = A[M][K] * Bt[N][K]^T ----
template <bool F32OUT>
__global__ __launch_bounds__(256) void k_gemm(const uint16_t* __restrict__ A,
                                              const uint16_t* __restrict__ Bt,
                                              void* __restrict__ Cp,
                                              int K, int ldc) {
  int lane = threadIdx.x & 63, wave = threadIdx.x >> 6;
  int lr = lane & 15, lg = lane >> 4;
  int m0 = blockIdx.y * 64 + wave * 16;
  int n0 = blockIdx.x * 64;
  f32x4 acc[4] = {};
  const uint16_t* pa = A + (size_t)(m0 + lr) * K + lg * 8;
  const uint16_t* pb = Bt + (size_t)(n0 + lr) * K + lg * 8;
#pragma unroll 4
  for (int k = 0; k < K; k += 32) {
    bf16x8 af = *(const bf16x8*)(pa + k);
#pragma unroll
    for (int c = 0; c < 4; c++) {
      bf16x8 bf = *(const bf16x8*)(pb + (size_t)c * 16 * K + k);
      acc[c] = mfma16(af, bf, acc[c]);
    }
  }
#pragma unroll
  for (int c = 0; c < 4; c++)
#pragma unroll
    for (int r = 0; r < 4; r++) {
      size_t idx = (size_t)(m0 + lg * 4 + r) * ldc + n0 + c * 16 + lr;
      if (F32OUT) ((float*)Cp)[idx] = acc[c][r];
      else        ((uint16_t*)Cp)[idx] = f2bf(acc[c][r]);
    }
}

// ---- V columns of QKV -> Vt[(b*16+h)][dv=64][t=2048] bf16 ----
__global__ __launch_bounds__(256) void k_vtrans(const uint16_t* __restrict__ QKV,
                                                uint16_t* __restrict__ Vt) {
  __shared__ uint16_t tile[64][72];
  int t0 = blockIdx.x * 64;
  int h = blockIdx.y, b = blockIdx.z;
  int vOff = (h < 8) ? (1024 + h * 64) : (2048 + (h - 8) * 64);
  const uint16_t* src = QKV + ((size_t)b * TT + t0) * 2560 + vOff;
  int tx = threadIdx.x & 15, ty = threadIdx.x >> 4;
#pragma unroll
  for (int p = 0; p < 4; p++)
    *(ushort4*)&tile[ty + p * 16][tx * 4] =
        *(const ushort4*)(src + (size_t)(ty + p * 16) * 2560 + tx * 4);
  __syncthreads();
  uint16_t* dst = Vt + ((size_t)(b * 16 + h) * 64) * TT + t0;
#pragma unroll
  for (int p = 0; p < 4; p++) {
    int dv = ty + p * 16;
    ushort4 o;
    o.x = tile[tx * 4 + 0][dv];
    o.y = tile[tx * 4 + 1][dv];
    o.z = tile[tx * 4 + 2][dv];
    o.w = tile[tx * 4 + 3][dv];
    *(ushort4*)(dst + (size_t)dv * TT + tx * 4) = o;
  }
}

// ---- windowed causal flash attention (swapped QK^T, O^T accum, V^T direct) ----
__global__ __launch_bounds__(256) void k_attn(const uint16_t* __restrict__ QKV,
                                              const uint16_t* __restrict__ Vt,
                                              uint16_t* __restrict__ Y) {
  __shared__ __align__(16) uint16_t Plds[4][16][40];   // P rows [q][key-local], padded
  const int lane = threadIdx.x & 63, wave = threadIdx.x >> 6;
  const int lr = lane & 15, lg = lane >> 4;
  const int qt = blockIdx.x & 31;
  const int h = (blockIdx.x >> 5) & 15;
  const int b = blockIdx.x >> 9;
  const int q0 = qt * 64 + wave * 16;

  int dqk, window, qOff, kOff;
  if (h < 8) { dqk = 64; window = 1024; qOff = h * 64; kOff = 512 + h * 64; }
  else { int hr = h - 8; dqk = 32; window = 256; qOff = 1536 + hr * 32; kOff = 1792 + hr * 32; }
  const float scale = (dqk == 64) ? 0.125f : 0.17677669529663687f;
  const uint16_t* base = QKV + (size_t)b * TT * 2560;
  const uint16_t* vt = Vt + ((size_t)(b * 16 + h) * 64) * TT;  // row dv: vt + dv*TT
  const int nf = dqk >> 5;

  // Q as B-fragment: lane holds Q[q0+lr][s*32 + lg*8 .. +7]
  bf16x8 qf[2];
  for (int s = 0; s < nf; s++)
    qf[s] = *(const bf16x8*)(base + (size_t)(q0 + lr) * 2560 + qOff + s * 32 + lg * 8);

  float m = NEGF, lsum = 0.f;
  f32x4 o[4] = {};   // O^T: o[db] holds rows dv=db*16+lg*4+r, col q=lr

  int klo = q0 - window + 1; if (klo < 0) klo = 0; klo &= ~31;
  const int khi = q0 + 15;
  const int q = q0 + lr;

  for (int k0 = klo; k0 <= khi; k0 += 32) {
    // ---- V^T fragments direct from global (L2-resident), issued early ----
    bf16x8 vf[4];
#pragma unroll
    for (int db = 0; db < 4; db++)
      vf[db] = *(const bf16x8*)(vt + (size_t)(db * 16 + lr) * TT + k0 + lg * 8);

    // ---- S^T = K·Q^T : lane reg r holds S^T[key=k0+16hh+lg*4+r][q=q0+lr] ----
    f32x4 st[2];
#pragma unroll
    for (int hh = 0; hh < 2; hh++) {
      f32x4 acc = {0.f, 0.f, 0.f, 0.f};
      const uint16_t* kp = base + (size_t)(k0 + 16 * hh + lr) * 2560 + kOff + lg * 8;
#pragma unroll
      for (int s = 0; s < nf; s++)
        acc = mfma16(*(const bf16x8*)(kp + s * 32), qf[s], acc);
      st[hh] = acc;
    }
    // ---- scale + window mask ----
    float tmax = NEGF;
    const bool interior = (k0 + 31 <= q0) && (k0 >= khi - window + 1);
    if (interior) {
#pragma unroll
      for (int hh = 0; hh < 2; hh++)
#pragma unroll
        for (int r = 0; r < 4; r++) {
          float sv = st[hh][r] * scale;
          st[hh][r] = sv;
          tmax = fmaxf(tmax, sv);
        }
    } else {
#pragma unroll
      for (int hh = 0; hh < 2; hh++)
#pragma unroll
        for (int r = 0; r < 4; r++) {
          int key = k0 + 16 * hh + lg * 4 + r;
          bool ok = (key <= q) && (q - key < window);
          float sv = ok ? st[hh][r] * scale : NEGF;
          st[hh][r] = sv;
          tmax = fmaxf(tmax, sv);
        }
    }
    tmax = fmaxf(tmax, __shfl_xor(tmax, 16));
    tmax = fmaxf(tmax, __shfl_xor(tmax, 32));
    // ---- online softmax (exact skip when no row's max grew) ----
    if (!__all(tmax <= m)) {
      float mn = fmaxf(m, tmax);
      float alpha = __expf(m - mn);
      lsum *= alpha;
#pragma unroll
      for (int d = 0; d < 4; d++) o[d] *= alpha;
      m = mn;
    }
    float psum = 0.f;
#pragma unroll
    for (int hh = 0; hh < 2; hh++) {
      bf16x4 pk;
#pragma unroll
      for (int r = 0; r < 4; r++) {
        float sv = st[hh][r];
        float p = (sv > -0.5e30f) ? __expf(sv - m) : 0.f;
        psum += p;
        pk[r] = (short)f2bf(p);
      }
      *(bf16x4*)&Plds[wave][lr][16 * hh + lg * 4] = pk;   // one 8B LDS write per half
    }
    psum += __shfl_xor(psum, 16);
    psum += __shfl_xor(psum, 32);
    lsum += psum;

    // P as B-fragment: P[q=lr][key-local lg*8..+7] (same-wave LDS is in-order;
    // plain HIP ds ops -> compiler inserts the lgkmcnt)
    bf16x8 pf = *(const bf16x8*)&Plds[wave][lr][lg * 8];
    // ---- O^T += V^T·P^T ----
#pragma unroll
    for (int db = 0; db < 4; db++)
      o[db] = mfma16(vf[db], pf, o[db]);
  }
  // ---- epilogue: normalize, write Y (lane owns row q=q0+lr) ----
  const float inv = 1.0f / lsum;
  uint16_t* yp = Y + ((size_t)b * TT + q0 + lr) * CC + h * 64;
#pragma unroll
  for (int db = 0; db < 4; db++)
#pragma unroll
    for (int r = 0; r < 4; r++)
      yp[db * 16 + lg * 4 + r] = f2bf(o[db][r] * inv);
}

extern "C" void kernel_launch(void* const* d_in, const int* in_sizes, int n_in,
                              void* d_out, int out_size, void* d_ws, size_t ws_size,
                              hipStream_t stream) {
  const float* x    = (const float*)d_in[0];
  const float* wqkv = (const float*)d_in[1];
  const float* wqk  = (const float*)d_in[2];
  const float* wv   = (const float*)d_in[3];
  const float* wp   = (const float*)d_in[4];

  uint16_t* ws  = (uint16_t*)d_ws;
  uint16_t* xb  = ws;                               // [4096][1024] (dead after QKV GEMM)
  uint16_t* WtA = xb  + (size_t)4096 * 1024;        // [2560][1024]
  uint16_t* WtP = WtA + (size_t)2560 * 1024;        // [1024][1024]
  uint16_t* QKV = WtP + (size_t)1024 * 1024;        // [4096][2560]
  uint16_t* Yb  = QKV + (size_t)4096 * 2560;        // [4096][1024]
  uint16_t* Vt  = xb;                               // alias: [32][64][2048] == 8 MB

  k_convert<<<4096, 256, 0, stream>>>(x, xb, 4096 * 1024 / 4);
  k_transpose<<<dim3(48, 32), 256, 0, stream>>>(wqkv, WtA, 1024, 1536);
  k_transpose<<<dim3(16, 32), 256, 0, stream>>>(wqk, WtA + (size_t)1536 * 1024, 1024, 512);
  k_transpose<<<dim3(16, 32), 256, 0, stream>>>(wv,  WtA + (size_t)2048 * 1024, 1024, 512);
  k_transpose<<<dim3(32, 32), 256, 0, stream>>>(wp,  WtP, 1024, 1024);
  k_gemm<false><<<dim3(40, 64), 256, 0, stream>>>(xb, WtA, QKV, 1024, 2560);
  k_vtrans<<<dim3(32, 16, 2), 256, 0, stream>>>(QKV, Vt);
  k_attn<<<1024, 256, 0, stream>>>(QKV, Vt, Yb);
  k_gemm<true><<<dim3(16, 64), 256, 0, stream>>>(Yb, WtP, (float*)d_out, 1024, 1024);
}

// Round 6
// 254.161 us; speedup vs baseline: 2.4493x; 1.8781x over previous
//
#include <hip/hip_runtime.h>
#include <hip/hip_bf16.h>
#include <stdint.h>

#define TT 2048
#define BB 2
#define CC 1024
#define NEGF (-1e30f)

typedef short bf16x8 __attribute__((ext_vector_type(8)));
typedef short bf16x4 __attribute__((ext_vector_type(4)));
typedef float f32x4 __attribute__((ext_vector_type(4)));

__device__ __forceinline__ f32x4 mfma16(bf16x8 a, bf16x8 b, f32x4 c) {
  return __builtin_amdgcn_mfma_f32_16x16x32_bf16(a, b, c, 0, 0, 0);
}

__device__ __forceinline__ uint16_t f2bf(float f) {
  union { float f; uint32_t u; } v; v.f = f;
  uint32_t u = v.u;
  return (uint16_t)((u + 0x7FFFu + ((u >> 16) & 1u)) >> 16);
}

typedef __attribute__((address_space(3))) uint32_t lds_u32;
typedef const __attribute__((address_space(1))) uint32_t glb_u32;
__device__ __forceinline__ void gload_lds16(const uint16_t* g, uint16_t* l) {
  __builtin_amdgcn_global_load_lds((glb_u32*)g, (lds_u32*)l, 16, 0, 0);
}

// ---- x f32 -> bf16 ----
__global__ __launch_bounds__(256) void k_convert(const float* __restrict__ in,
                                                 uint16_t* __restrict__ out, int n4) {
  int i = blockIdx.x * blockDim.x + threadIdx.x;
  if (i >= n4) return;
  float4 f = ((const float4*)in)[i];
  ushort4 o;
  o.x = f2bf(f.x); o.y = f2bf(f.y); o.z = f2bf(f.z); o.w = f2bf(f.w);
  ((ushort4*)out)[i] = o;
}

// ---- W [K][N] f32 -> Wt [N][K] bf16 (LDS-tiled transpose) ----
__global__ __launch_bounds__(256) void k_transpose(const float* __restrict__ W,
                                                   uint16_t* __restrict__ Wt,
                                                   int K, int N) {
  __shared__ float tile[32][33];
  int tx = threadIdx.x & 31, ty = threadIdx.x >> 5;
  int n0 = blockIdx.x * 32, k0 = blockIdx.y * 32;
#pragma unroll
  for (int r = 0; r < 4; r++)
    tile[ty + r * 8][tx] = W[(size_t)(k0 + ty + r * 8) * N + n0 + tx];
  __syncthreads();
#pragma unroll
  for (int r = 0; r < 4; r++)
    Wt[(size_t)(n0 + ty + r * 8) * K + k0 + tx] = f2bf(tile[tx][ty + r * 8]);
}

// ---- GEMM (m97 structure): C[M][ldc] = A[M][K] * Bt[N][K]^T ----
// 128x128 block tile, BK=32, 4 waves (2x2), global_load_lds width=16.
template <bool F32OUT>
__global__ __launch_bounds__(256) void k_gemm128(const uint16_t* __restrict__ A,
                                                 const uint16_t* __restrict__ Bt,
                                                 void* __restrict__ Cp,
                                                 int K, int ldc) {
  __shared__ __align__(16) uint16_t Alds[128 * 32];
  __shared__ __align__(16) uint16_t Blds[128 * 32];
  const int tid = threadIdx.x;
  const int lane = tid & 63, wave = tid >> 6;
  const int lr = lane & 15, lg = lane >> 4;
  const int wm = wave & 1, wn = wave >> 1;       // 2x2 wave grid, 64x64 each
  const int m0 = blockIdx.y * 128;
  const int n0 = blockIdx.x * 128;

  f32x4 acc[4][4] = {};

  // staging: chunk c (0..511) = 16B; row = c>>2, col8 = (c&3)*8; LDS linear.
  // wave w, round R stages chunks R*256 + w*64 + lane.
  const int srow = wave * 16 + (lane >> 2);       // + R*64
  const int scol = (lane & 3) * 8;
  const uint16_t* pa_l = A + (size_t)(m0 + srow) * K + scol;
  const uint16_t* pb_l = Bt + (size_t)(n0 + srow) * K + scol;
  uint16_t* alds_w0 = &Alds[(wave * 64) * 8];     // uniform per wave
  uint16_t* alds_w1 = &Alds[(256 + wave * 64) * 8];
  uint16_t* blds_w0 = &Blds[(wave * 64) * 8];
  uint16_t* blds_w1 = &Blds[(256 + wave * 64) * 8];

  for (int k0 = 0; k0 < K; k0 += 32) {
    __syncthreads();                               // prev-tile reads done
    gload_lds16(pa_l + k0, alds_w0);
    gload_lds16(pa_l + (size_t)64 * K + k0, alds_w1);
    gload_lds16(pb_l + k0, blds_w0);
    gload_lds16(pb_l + (size_t)64 * K + k0, blds_w1);
    __syncthreads();                               // staging complete

    bf16x8 af[4], bfr[4];
#pragma unroll
    for (int mi = 0; mi < 4; mi++)
      af[mi] = *(const bf16x8*)&Alds[(wm * 64 + mi * 16 + lr) * 32 + lg * 8];
#pragma unroll
    for (int ni = 0; ni < 4; ni++)
      bfr[ni] = *(const bf16x8*)&Blds[(wn * 64 + ni * 16 + lr) * 32 + lg * 8];
#pragma unroll
    for (int mi = 0; mi < 4; mi++)
#pragma unroll
      for (int ni = 0; ni < 4; ni++)
        acc[mi][ni] = mfma16(af[mi], bfr[ni], acc[mi][ni]);
  }

#pragma unroll
  for (int mi = 0; mi < 4; mi++)
#pragma unroll
    for (int ni = 0; ni < 4; ni++)
#pragma unroll
      for (int r = 0; r < 4; r++) {
        size_t idx = (size_t)(m0 + wm * 64 + mi * 16 + lg * 4 + r) * ldc
                   + n0 + wn * 64 + ni * 16 + lr;
        if (F32OUT) ((float*)Cp)[idx] = acc[mi][ni][r];
        else        ((uint16_t*)Cp)[idx] = f2bf(acc[mi][ni][r]);
      }
}

// ---- V columns of QKV -> Vt[(b*16+h)][dv=64][t=2048] bf16 ----
__global__ __launch_bounds__(256) void k_vtrans(const uint16_t* __restrict__ QKV,
                                                uint16_t* __restrict__ Vt) {
  __shared__ uint16_t tile[64][72];
  int t0 = blockIdx.x * 64;
  int h = blockIdx.y, b = blockIdx.z;
  int vOff = (h < 8) ? (1024 + h * 64) : (2048 + (h - 8) * 64);
  const uint16_t* src = QKV + ((size_t)b * TT + t0) * 2560 + vOff;
  int tx = threadIdx.x & 15, ty = threadIdx.x >> 4;
#pragma unroll
  for (int p = 0; p < 4; p++)
    *(ushort4*)&tile[ty + p * 16][tx * 4] =
        *(const ushort4*)(src + (size_t)(ty + p * 16) * 2560 + tx * 4);
  __syncthreads();
  uint16_t* dst = Vt + ((size_t)(b * 16 + h) * 64) * TT + t0;
#pragma unroll
  for (int p = 0; p < 4; p++) {
    int dv = ty + p * 16;
    ushort4 o;
    o.x = tile[tx * 4 + 0][dv];
    o.y = tile[tx * 4 + 1][dv];
    o.z = tile[tx * 4 + 2][dv];
    o.w = tile[tx * 4 + 3][dv];
    *(ushort4*)(dst + (size_t)dv * TT + tx * 4) = o;
  }
}

// ---- windowed causal flash attention (swapped QK^T, O^T accum, V^T direct) ----
__global__ __launch_bounds__(256) void k_attn(const uint16_t* __restrict__ QKV,
                                              const uint16_t* __restrict__ Vt,
                                              uint16_t* __restrict__ Y) {
  __shared__ __align__(16) uint16_t Plds[4][16][40];
  const int lane = threadIdx.x & 63, wave = threadIdx.x >> 6;
  const int lr = lane & 15, lg = lane >> 4;
  const int qt = blockIdx.x & 31;
  const int h = (blockIdx.x >> 5) & 15;
  const int b = blockIdx.x >> 9;
  const int q0 = qt * 64 + wave * 16;

  int dqk, window, qOff, kOff;
  if (h < 8) { dqk = 64; window = 1024; qOff = h * 64; kOff = 512 + h * 64; }
  else { int hr = h - 8; dqk = 32; window = 256; qOff = 1536 + hr * 32; kOff = 1792 + hr * 32; }
  const float scale = (dqk == 64) ? 0.125f : 0.17677669529663687f;
  const uint16_t* base = QKV + (size_t)b * TT * 2560;
  const uint16_t* vt = Vt + ((size_t)(b * 16 + h) * 64) * TT;
  const int nf = dqk >> 5;

  bf16x8 qf[2];
  for (int s = 0; s < nf; s++)
    qf[s] = *(const bf16x8*)(base + (size_t)(q0 + lr) * 2560 + qOff + s * 32 + lg * 8);

  float m = NEGF, lsum = 0.f;
  f32x4 o[4] = {};

  int klo = q0 - window + 1; if (klo < 0) klo = 0; klo &= ~31;
  const int khi = q0 + 15;
  const int q = q0 + lr;

  for (int k0 = klo; k0 <= khi; k0 += 32) {
    bf16x8 vf[4];
#pragma unroll
    for (int db = 0; db < 4; db++)
      vf[db] = *(const bf16x8*)(vt + (size_t)(db * 16 + lr) * TT + k0 + lg * 8);

    f32x4 st[2];
#pragma unroll
    for (int hh = 0; hh < 2; hh++) {
      f32x4 acc = {0.f, 0.f, 0.f, 0.f};
      const uint16_t* kp = base + (size_t)(k0 + 16 * hh + lr) * 2560 + kOff + lg * 8;
#pragma unroll
      for (int s = 0; s < nf; s++)
        acc = mfma16(*(const bf16x8*)(kp + s * 32), qf[s], acc);
      st[hh] = acc;
    }
    float tmax = NEGF;
    const bool interior = (k0 + 31 <= q0) && (k0 >= khi - window + 1);
    if (interior) {
#pragma unroll
      for (int hh = 0; hh < 2; hh++)
#pragma unroll
        for (int r = 0; r < 4; r++) {
          float sv = st[hh][r] * scale;
          st[hh][r] = sv;
          tmax = fmaxf(tmax, sv);
        }
    } else {
#pragma unroll
      for (int hh = 0; hh < 2; hh++)
#pragma unroll
        for (int r = 0; r < 4; r++) {
          int key = k0 + 16 * hh + lg * 4 + r;
          bool ok = (key <= q) && (q - key < window);
          float sv = ok ? st[hh][r] * scale : NEGF;
          st[hh][r] = sv;
          tmax = fmaxf(tmax, sv);
        }
    }
    tmax = fmaxf(tmax, __shfl_xor(tmax, 16));
    tmax = fmaxf(tmax, __shfl_xor(tmax, 32));
    if (!__all(tmax <= m)) {
      float mn = fmaxf(m, tmax);
      float alpha = __expf(m - mn);
      lsum *= alpha;
#pragma unroll
      for (int d = 0; d < 4; d++) o[d] *= alpha;
      m = mn;
    }
    float psum = 0.f;
#pragma unroll
    for (int hh = 0; hh < 2; hh++) {
      bf16x4 pk;
#pragma unroll
      for (int r = 0; r < 4; r++) {
        float sv = st[hh][r];
        float p = (sv > -0.5e30f) ? __expf(sv - m) : 0.f;
        psum += p;
        pk[r] = (short)f2bf(p);
      }
      *(bf16x4*)&Plds[wave][lr][16 * hh + lg * 4] = pk;
    }
    psum += __shfl_xor(psum, 16);
    psum += __shfl_xor(psum, 32);
    lsum += psum;

    bf16x8 pf = *(const bf16x8*)&Plds[wave][lr][lg * 8];
#pragma unroll
    for (int db = 0; db < 4; db++)
      o[db] = mfma16(vf[db], pf, o[db]);
  }
  const float inv = 1.0f / lsum;
  uint16_t* yp = Y + ((size_t)b * TT + q0 + lr) * CC + h * 64;
#pragma unroll
  for (int db = 0; db < 4; db++)
#pragma unroll
    for (int r = 0; r < 4; r++)
      yp[db * 16 + lg * 4 + r] = f2bf(o[db][r] * inv);
}

extern "C" void kernel_launch(void* const* d_in, const int* in_sizes, int n_in,
                              void* d_out, int out_size, void* d_ws, size_t ws_size,
                              hipStream_t stream) {
  const float* x    = (const float*)d_in[0];
  const float* wqkv = (const float*)d_in[1];
  const float* wqk  = (const float*)d_in[2];
  const float* wv   = (const float*)d_in[3];
  const float* wp   = (const float*)d_in[4];

  uint16_t* ws  = (uint16_t*)d_ws;
  uint16_t* xb  = ws;                               // [4096][1024] (dead after QKV GEMM)
  uint16_t* WtA = xb  + (size_t)4096 * 1024;        // [2560][1024]
  uint16_t* WtP = WtA + (size_t)2560 * 1024;        // [1024][1024]
  uint16_t* QKV = WtP + (size_t)1024 * 1024;        // [4096][2560]
  uint16_t* Yb  = QKV + (size_t)4096 * 2560;        // [4096][1024]
  uint16_t* Vt  = xb;                               // alias after GEMM: [32][64][2048]

  k_convert<<<4096, 256, 0, stream>>>(x, xb, 4096 * 1024 / 4);
  k_transpose<<<dim3(48, 32), 256, 0, stream>>>(wqkv, WtA, 1024, 1536);
  k_transpose<<<dim3(16, 32), 256, 0, stream>>>(wqk, WtA + (size_t)1536 * 1024, 1024, 512);
  k_transpose<<<dim3(16, 32), 256, 0, stream>>>(wv,  WtA + (size_t)2048 * 1024, 1024, 512);
  k_transpose<<<dim3(32, 32), 256, 0, stream>>>(wp,  WtP, 1024, 1024);
  k_gemm128<false><<<dim3(20, 32), 256, 0, stream>>>(xb, WtA, QKV, 1024, 2560);
  k_vtrans<<<dim3(32, 16, 2), 256, 0, stream>>>(QKV, Vt);
  k_attn<<<1024, 256, 0, stream>>>(QKV, Vt, Yb);
  k_gemm128<true><<<dim3(8, 32), 256, 0, stream>>>(Yb, WtP, (float*)d_out, 1024, 1024);
}

// Round 8
// 203.863 us; speedup vs baseline: 3.0536x; 1.2467x over previous
//
#include <hip/hip_runtime.h>
#include <hip/hip_bf16.h>
#include <stdint.h>

#define TT 2048
#define BB 2
#define CC 1024
#define NEGF (-1e30f)

typedef short bf16x8 __attribute__((ext_vector_type(8)));
typedef short bf16x4 __attribute__((ext_vector_type(4)));
typedef float f32x4 __attribute__((ext_vector_type(4)));

__device__ __forceinline__ f32x4 mfma16(bf16x8 a, bf16x8 b, f32x4 c) {
  return __builtin_amdgcn_mfma_f32_16x16x32_bf16(a, b, c, 0, 0, 0);
}

__device__ __forceinline__ uint16_t f2bf(float f) {
  union { float f; uint32_t u; } v; v.f = f;
  uint32_t u = v.u;
  return (uint16_t)((u + 0x7FFFu + ((u >> 16) & 1u)) >> 16);
}

typedef __attribute__((address_space(3))) uint32_t lds_u32;
typedef const __attribute__((address_space(1))) uint32_t glb_u32;
__device__ __forceinline__ void gload_lds16(const uint16_t* g, uint16_t* l) {
  __builtin_amdgcn_global_load_lds((glb_u32*)g, (lds_u32*)l, 16, 0, 0);
}

// ---- x f32 -> bf16 ----
__global__ __launch_bounds__(256) void k_convert(const float* __restrict__ in,
                                                 uint16_t* __restrict__ out, int n4) {
  int i = blockIdx.x * blockDim.x + threadIdx.x;
  if (i >= n4) return;
  float4 f = ((const float4*)in)[i];
  ushort4 o;
  o.x = f2bf(f.x); o.y = f2bf(f.y); o.z = f2bf(f.z); o.w = f2bf(f.w);
  ((ushort4*)out)[i] = o;
}

// ---- W [K][N] f32 -> Wt [N][K] bf16 (LDS-tiled transpose) ----
__global__ __launch_bounds__(256) void k_transpose(const float* __restrict__ W,
                                                   uint16_t* __restrict__ Wt,
                                                   int K, int N) {
  __shared__ float tile[32][33];
  int tx = threadIdx.x & 31, ty = threadIdx.x >> 5;
  int n0 = blockIdx.x * 32, k0 = blockIdx.y * 32;
#pragma unroll
  for (int r = 0; r < 4; r++)
    tile[ty + r * 8][tx] = W[(size_t)(k0 + ty + r * 8) * N + n0 + tx];
  __syncthreads();
#pragma unroll
  for (int r = 0; r < 4; r++)
    Wt[(size_t)(n0 + ty + r * 8) * K + k0 + tx] = f2bf(tile[tx][ty + r * 8]);
}

// ---- GEMM (m97 structure): C[M][ldc] = A[M][K] * Bt[N][K]^T ----
template <bool F32OUT>
__global__ __launch_bounds__(256) void k_gemm128(const uint16_t* __restrict__ A,
                                                 const uint16_t* __restrict__ Bt,
                                                 void* __restrict__ Cp,
                                                 int K, int ldc) {
  __shared__ __align__(16) uint16_t Alds[128 * 32];
  __shared__ __align__(16) uint16_t Blds[128 * 32];
  const int tid = threadIdx.x;
  const int lane = tid & 63, wave = tid >> 6;
  const int lr = lane & 15, lg = lane >> 4;
  const int wm = wave & 1, wn = wave >> 1;
  const int m0 = blockIdx.y * 128;
  const int n0 = blockIdx.x * 128;

  f32x4 acc[4][4] = {};

  const int srow = wave * 16 + (lane >> 2);
  const int scol = (lane & 3) * 8;
  const uint16_t* pa_l = A + (size_t)(m0 + srow) * K + scol;
  const uint16_t* pb_l = Bt + (size_t)(n0 + srow) * K + scol;
  uint16_t* alds_w0 = &Alds[(wave * 64) * 8];
  uint16_t* alds_w1 = &Alds[(256 + wave * 64) * 8];
  uint16_t* blds_w0 = &Blds[(wave * 64) * 8];
  uint16_t* blds_w1 = &Blds[(256 + wave * 64) * 8];

  for (int k0 = 0; k0 < K; k0 += 32) {
    __syncthreads();
    gload_lds16(pa_l + k0, alds_w0);
    gload_lds16(pa_l + (size_t)64 * K + k0, alds_w1);
    gload_lds16(pb_l + k0, blds_w0);
    gload_lds16(pb_l + (size_t)64 * K + k0, blds_w1);
    __syncthreads();

    bf16x8 af[4], bfr[4];
#pragma unroll
    for (int mi = 0; mi < 4; mi++)
      af[mi] = *(const bf16x8*)&Alds[(wm * 64 + mi * 16 + lr) * 32 + lg * 8];
#pragma unroll
    for (int ni = 0; ni < 4; ni++)
      bfr[ni] = *(const bf16x8*)&Blds[(wn * 64 + ni * 16 + lr) * 32 + lg * 8];
#pragma unroll
    for (int mi = 0; mi < 4; mi++)
#pragma unroll
      for (int ni = 0; ni < 4; ni++)
        acc[mi][ni] = mfma16(af[mi], bfr[ni], acc[mi][ni]);
  }

#pragma unroll
  for (int mi = 0; mi < 4; mi++)
#pragma unroll
    for (int ni = 0; ni < 4; ni++)
#pragma unroll
      for (int r = 0; r < 4; r++) {
        size_t idx = (size_t)(m0 + wm * 64 + mi * 16 + lg * 4 + r) * ldc
                   + n0 + wn * 64 + ni * 16 + lr;
        if (F32OUT) ((float*)Cp)[idx] = acc[mi][ni][r];
        else        ((uint16_t*)Cp)[idx] = f2bf(acc[mi][ni][r]);
      }
}

// ---- V columns of QKV -> Vt[(b*16+h)][dv=64][t=2048] bf16 ----
__global__ __launch_bounds__(256) void k_vtrans(const uint16_t* __restrict__ QKV,
                                                uint16_t* __restrict__ Vt) {
  __shared__ uint16_t tile[64][72];
  int t0 = blockIdx.x * 64;
  int h = blockIdx.y, b = blockIdx.z;
  int vOff = (h < 8) ? (1024 + h * 64) : (2048 + (h - 8) * 64);
  const uint16_t* src = QKV + ((size_t)b * TT + t0) * 2560 + vOff;
  int tx = threadIdx.x & 15, ty = threadIdx.x >> 4;
#pragma unroll
  for (int p = 0; p < 4; p++)
    *(ushort4*)&tile[ty + p * 16][tx * 4] =
        *(const ushort4*)(src + (size_t)(ty + p * 16) * 2560 + tx * 4);
  __syncthreads();
  uint16_t* dst = Vt + ((size_t)(b * 16 + h) * 64) * TT + t0;
#pragma unroll
  for (int p = 0; p < 4; p++) {
    int dv = ty + p * 16;
    ushort4 o;
    o.x = tile[tx * 4 + 0][dv];
    o.y = tile[tx * 4 + 1][dv];
    o.z = tile[tx * 4 + 2][dv];
    o.w = tile[tx * 4 + 3][dv];
    *(ushort4*)(dst + (size_t)dv * TT + tx * 4) = o;
  }
}

// ---- windowed causal flash attention ----
// KVBLK=64; K,V staged in block-shared LDS via global_load_lds with XOR
// chunk-swizzle (chunk ^= row&7) applied to BOTH staging source and ds_read.
__global__ __launch_bounds__(256) void k_attn(const uint16_t* __restrict__ QKV,
                                              const uint16_t* __restrict__ Vt,
                                              uint16_t* __restrict__ Y) {
  __shared__ __align__(16) uint16_t Klds[64 * 64];     // [key][dqk] swizzled
  __shared__ __align__(16) uint16_t Vlds[64 * 64];     // [dv][key] swizzled
  __shared__ __align__(16) uint16_t Plds[4][16][72];   // per-wave P[q][key]
  const int tid = threadIdx.x;
  const int lane = tid & 63, wave = tid >> 6;
  const int lr = lane & 15, lg = lane >> 4;
  const int qt = blockIdx.x & 31;
  const int h = (blockIdx.x >> 5) & 15;
  const int b = blockIdx.x >> 9;
  const int q0b = qt * 64;
  const int q0 = q0b + wave * 16;

  int dqk, window, qOff, kOff;
  if (h < 8) { dqk = 64; window = 1024; qOff = h * 64; kOff = 512 + h * 64; }
  else { int hr = h - 8; dqk = 32; window = 256; qOff = 1536 + hr * 32; kOff = 1792 + hr * 32; }
  const float scale = (dqk == 64) ? 0.125f : 0.17677669529663687f;
  const uint16_t* base = QKV + (size_t)b * TT * 2560;
  const uint16_t* vt = Vt + ((size_t)(b * 16 + h) * 64) * TT;
  const int nf = dqk >> 5;

  bf16x8 qf[2];
  for (int s = 0; s < nf; s++)
    qf[s] = *(const bf16x8*)(base + (size_t)(q0 + lr) * 2560 + qOff + s * 32 + lg * 8);

  float m = NEGF, lsum = 0.f;
  f32x4 o[4] = {};

  int klo_b = q0b - window + 1; if (klo_b < 0) klo_b = 0; klo_b &= ~63;
  const int klo_w = (q0 - window + 1 < 0) ? 0 : (q0 - window + 1);
  const int khi_w = q0 + 15;
  const int q = q0 + lr;

  for (int k0 = klo_b; k0 <= q0b + 63; k0 += 64) {
    __syncthreads();                                   // prev-tile LDS reads done
    // ---- stage K tile [64 keys][dqk], chunk-swizzled ----
    if (nf == 2) {
#pragma unroll
      for (int j = 0; j < 2; j++) {
        int c = j * 256 + tid;
        int row = c >> 3, cl = c & 7, sc = cl ^ (row & 7);
        gload_lds16(base + (size_t)(k0 + row) * 2560 + kOff + sc * 8,
                    &Klds[(j * 256 + wave * 64) * 8]);
      }
    } else {
      int row = tid >> 2, cl = tid & 3, sc = cl ^ (row & 3);
      gload_lds16(base + (size_t)(k0 + row) * 2560 + kOff + sc * 8,
                  &Klds[(wave * 64) * 8]);
    }
    // ---- stage V^T tile [64 dv][64 keys], chunk-swizzled ----
#pragma unroll
    for (int j = 0; j < 2; j++) {
      int c = j * 256 + tid;
      int row = c >> 3, cl = c & 7, sc = cl ^ (row & 7);
      gload_lds16(vt + (size_t)row * TT + k0 + sc * 8,
                  &Vlds[(j * 256 + wave * 64) * 8]);
    }
    __syncthreads();                                   // staging drained

    if (k0 > khi_w || k0 + 63 < klo_w) continue;       // wave-uniform skip

    // ---- S^T = K·Q^T over 4 key-halves ----
    f32x4 st[4];
#pragma unroll
    for (int hh = 0; hh < 4; hh++) {
      f32x4 acc = {0.f, 0.f, 0.f, 0.f};
      int row = hh * 16 + lr;
      if (nf == 2) {
        acc = mfma16(*(const bf16x8*)&Klds[row * 64 + ((lg) ^ (row & 7)) * 8], qf[0], acc);
        acc = mfma16(*(const bf16x8*)&Klds[row * 64 + ((4 + lg) ^ (row & 7)) * 8], qf[1], acc);
      } else {
        acc = mfma16(*(const bf16x8*)&Klds[row * 32 + ((lg) ^ (row & 3)) * 8], qf[0], acc);
      }
      st[hh] = acc;
    }
    // ---- scale + window mask ----
    float tmax = NEGF;
    const bool interior = (k0 + 63 <= q0) && (q0 + 15 - k0 < window);
    if (interior) {
#pragma unroll
      for (int hh = 0; hh < 4; hh++)
#pragma unroll
        for (int r = 0; r < 4; r++) {
          float sv = st[hh][r] * scale;
          st[hh][r] = sv;
          tmax = fmaxf(tmax, sv);
        }
    } else {
#pragma unroll
      for (int hh = 0; hh < 4; hh++)
#pragma unroll
        for (int r = 0; r < 4; r++) {
          int key = k0 + 16 * hh + lg * 4 + r;
          bool ok = (key <= q) && (q - key < window);
          float sv = ok ? st[hh][r] * scale : NEGF;
          st[hh][r] = sv;
          tmax = fmaxf(tmax, sv);
        }
    }
    tmax = fmaxf(tmax, __shfl_xor(tmax, 16));
    tmax = fmaxf(tmax, __shfl_xor(tmax, 32));
    // ---- online softmax (skip rescale when no row's max grew) ----
    if (!__all(tmax <= m)) {
      float mn = fmaxf(m, tmax);
      float alpha = __expf(m - mn);
      lsum *= alpha;
#pragma unroll
      for (int d = 0; d < 4; d++) o[d] *= alpha;
      m = mn;
    }
    float psum = 0.f;
#pragma unroll
    for (int hh = 0; hh < 4; hh++) {
      bf16x4 pk;
#pragma unroll
      for (int r = 0; r < 4; r++) {
        float sv = st[hh][r];
        float p = (sv > -0.5e30f) ? __expf(sv - m) : 0.f;
        psum += p;
        pk[r] = (short)f2bf(p);
      }
      *(bf16x4*)&Plds[wave][lr][16 * hh + lg * 4] = pk;
    }
    psum += __shfl_xor(psum, 16);
    psum += __shfl_xor(psum, 32);
    lsum += psum;

    // ---- O^T += V^T·P^T over 2 key-slices ----
#pragma unroll
    for (int ks = 0; ks < 2; ks++) {
      bf16x8 pf = *(const bf16x8*)&Plds[wave][lr][ks * 32 + lg * 8];
#pragma unroll
      for (int db = 0; db < 4; db++) {
        int row = db * 16 + lr;
        bf16x8 vf = *(const bf16x8*)&Vlds[row * 64 + ((4 * ks + lg) ^ (row & 7)) * 8];
        o[db] = mfma16(vf, pf, o[db]);
      }
    }
  }
  // ---- epilogue ----
  const float inv = 1.0f / lsum;
  uint16_t* yp = Y + ((size_t)b * TT + q0 + lr) * CC + h * 64;
#pragma unroll
  for (int db = 0; db < 4; db++)
#pragma unroll
    for (int r = 0; r < 4; r++)
      yp[db * 16 + lg * 4 + r] = f2bf(o[db][r] * inv);
}

extern "C" void kernel_launch(void* const* d_in, const int* in_sizes, int n_in,
                              void* d_out, int out_size, void* d_ws, size_t ws_size,
                              hipStream_t stream) {
  const float* x    = (const float*)d_in[0];
  const float* wqkv = (const float*)d_in[1];
  const float* wqk  = (const float*)d_in[2];
  const float* wv   = (const float*)d_in[3];
  const float* wp   = (const float*)d_in[4];

  uint16_t* ws  = (uint16_t*)d_ws;
  uint16_t* xb  = ws;                               // [4096][1024] (dead after QKV GEMM)
  uint16_t* WtA = xb  + (size_t)4096 * 1024;        // [2560][1024]
  uint16_t* WtP = WtA + (size_t)2560 * 1024;        // [1024][1024]
  uint16_t* QKV = WtP + (size_t)1024 * 1024;        // [4096][2560]
  uint16_t* Yb  = QKV + (size_t)4096 * 2560;        // [4096][1024]
  uint16_t* Vt  = xb;                               // alias after GEMM: [32][64][2048]

  k_convert<<<4096, 256, 0, stream>>>(x, xb, 4096 * 1024 / 4);
  k_transpose<<<dim3(48, 32), 256, 0, stream>>>(wqkv, WtA, 1024, 1536);
  k_transpose<<<dim3(16, 32), 256, 0, stream>>>(wqk, WtA + (size_t)1536 * 1024, 1024, 512);
  k_transpose<<<dim3(16, 32), 256, 0, stream>>>(wv,  WtA + (size_t)2048 * 1024, 1024, 512);
  k_transpose<<<dim3(32, 32), 256, 0, stream>>>(wp,  WtP, 1024, 1024);
  k_gemm128<false><<<dim3(20, 32), 256, 0, stream>>>(xb, WtA, QKV, 1024, 2560);
  k_vtrans<<<dim3(32, 16, 2), 256, 0, stream>>>(QKV, Vt);
  k_attn<<<1024, 256, 0, stream>>>(QKV, Vt, Yb);
  k_gemm128<true><<<dim3(8, 32), 256, 0, stream>>>(Yb, WtP, (float*)d_out, 1024, 1024);
}